// Round 4
// baseline (955.693 us; speedup 1.0000x reference)
//
#include <hip/hip_runtime.h>

#define Bsz 512
#define Lsz 512
#define Tsz 128
#define TAG_START 126
#define TAG_STOP 127

typedef float v2f __attribute__((ext_vector_type(2)));
typedef float v4f __attribute__((ext_vector_type(4)));

__device__ __forceinline__ float rl(float v, int j) {
  return __int_as_float(__builtin_amdgcn_readlane(__float_as_int(v), j));
}
__device__ __forceinline__ float wave_max(float v) {
  #pragma unroll
  for (int off = 32; off > 0; off >>= 1) v = fmaxf(v, __shfl_down(v, off, 64));
  return v;
}
__device__ __forceinline__ float wave_sum(float v) {
  #pragma unroll
  for (int off = 32; off > 0; off >>= 1) v += __shfl_down(v, off, 64);
  return v;
}

// CDNA packed fp32 FMA: two fp32 FMAs per instruction.
__device__ __forceinline__ v2f pk_fma(v2f a, v2f b, v2f c) {
  v2f d;
  asm("v_pk_fma_f32 %0, %1, %2, %3" : "=v"(d) : "v"(a), "v"(b), "v"(c));
  return d;
}

// ONE WAVE per sequence. Lane j owns next-tags j and j+64; both expT rows
// live in VGPRs as float2 pairs (256 VGPRs). u[128] sits in LDS, written
// and re-read by the same wave each step: DS ops are in-order within a
// wave, so NO barrier anywhere in the 512-step scan. u-reads are
// wave-uniform b128 broadcasts; p1 normalizer via one v_readlane.
//
// Carry (exact, validated absmax=0 in R2/R3):
//   u_next = p * rcp(p1) * exp(emit),  m += log(p1),
//   fv materialized once at t == len-1.
__global__ __launch_bounds__(64, 1) void crf_fwd_kernel(
    const float* __restrict__ feats, const float* __restrict__ trans,
    const int* __restrict__ tags, const int* __restrict__ lens,
    float* __restrict__ diff_out)
{
  __shared__ __align__(16) float u_lds[Tsz];

  const int b = blockIdx.x;
  const int j = threadIdx.x;            // lane; owns tags j and j+64
  const int len = lens[b];
  const float* fb = feats + (size_t)b * Lsz * Tsz;

  // er0[i] = exp(trans[j][2i..2i+1]), er1[i] = exp(trans[j+64][2i..2i+1])
  v2f er0[64], er1[64];
  {
    const v4f* r0 = (const v4f*)(trans + (size_t)j * Tsz);
    const v4f* r1 = (const v4f*)(trans + (size_t)(j + 64) * Tsz);
    #pragma unroll
    for (int i = 0; i < 32; ++i) {
      v4f q0 = r0[i], q1 = r1[i];
      er0[2*i]   = (v2f){__expf(q0.x), __expf(q0.y)};
      er0[2*i+1] = (v2f){__expf(q0.z), __expf(q0.w)};
      er1[2*i]   = (v2f){__expf(q1.x), __expf(q1.y)};
      er1[2*i+1] = (v2f){__expf(q1.z), __expf(q1.w)};
    }
  }

  // u_0: 1 at START (tag 126 = lane 62's upper row), else 0
  u_lds[j]      = 0.0f;
  u_lds[j + 64] = (j + 64 == TAG_START) ? 1.0f : 0.0f;

  // 4-deep emission prefetch ring (registers)
  int i1 = (1 < len) ? 1 : len - 1;
  int i2 = (2 < len) ? 2 : len - 1;
  int i3 = (3 < len) ? 3 : len - 1;
  float ea0 = fb[j],                 eb0 = fb[j + 64];
  float ea1 = fb[(size_t)i1*Tsz+j],  eb1 = fb[(size_t)i1*Tsz+j+64];
  float ea2 = fb[(size_t)i2*Tsz+j],  eb2 = fb[(size_t)i2*Tsz+j+64];
  float ea3 = fb[(size_t)i3*Tsz+j],  eb3 = fb[(size_t)i3*Tsz+j+64];

  float m = 0.0f, fva = 0.0f, fvb = 0.0f;

  for (int t = 0; t < len; ++t) {
    int tp = t + 4; tp = (tp < len) ? tp : (len - 1);
    float na = fb[(size_t)tp * Tsz + j];
    float nb = fb[(size_t)tp * Tsz + j + 64];
    float ee0 = __expf(ea0), ee1 = __expf(eb0);     // off critical path

    v2f z = (v2f){0.f, 0.f};
    v2f a0[4] = {z, z, z, z}, a1[4] = {z, z, z, z};
    const v4f* up = (const v4f*)u_lds;
    #pragma unroll
    for (int i = 0; i < 32; ++i) {
      v4f q = up[i];                                 // wave-uniform broadcast
      v2f lo = __builtin_shufflevector(q, q, 0, 1);
      v2f hi = __builtin_shufflevector(q, q, 2, 3);
      a0[(2*i)   & 3] = pk_fma(er0[2*i],   lo, a0[(2*i)   & 3]);
      a1[(2*i)   & 3] = pk_fma(er1[2*i],   lo, a1[(2*i)   & 3]);
      a0[(2*i+1) & 3] = pk_fma(er0[2*i+1], hi, a0[(2*i+1) & 3]);
      a1[(2*i+1) & 3] = pk_fma(er1[2*i+1], hi, a1[(2*i+1) & 3]);
    }
    v2f s0 = (a0[0] + a0[1]) + (a0[2] + a0[3]);
    v2f s1 = (a1[0] + a1[1]) + (a1[2] + a1[3]);
    float p0 = s0.x + s0.y;                          // p for tag j
    float p1r = s1.x + s1.y;                         // p for tag j+64

    float p1 = rl(p0, 1);                            // tag 1's p
    float r = __builtin_amdgcn_rcpf(p1);
    if (t == len - 1) {
      fva = ea0 + m + __logf(p0);
      fvb = eb0 + m + __logf(p1r);
    }
    u_lds[j]      = p0  * r * ee0;   // in-order DS: next reads see these
    u_lds[j + 64] = p1r * r * ee1;
    m += __logf(p1);                                 // off critical path
    ea0 = ea1; ea1 = ea2; ea2 = ea3; ea3 = na;
    eb0 = eb1; eb1 = eb2; eb2 = eb3; eb3 = nb;
  }

  // terminal logsumexp over all 128 tags of fv + trans[START, tag]
  float x0 = fva + trans[TAG_START * Tsz + j];
  float x1 = fvb + trans[TAG_START * Tsz + j + 64];
  float mx = rl(wave_max(fmaxf(x0, x1)), 0);
  float se = rl(wave_sum(__expf(x0 - mx) + __expf(x1 - mx)), 0);
  float fwd_score = mx + __logf(se);

  // ---- gold score (fused) ----
  const int* tg = tags + (size_t)b * Lsz;
  float acc = 0.0f;
  for (int pos = j; pos <= len; pos += 64) {
    int st = (pos == 0)   ? TAG_START : tg[pos - 1];
    int et = (pos == len) ? TAG_STOP  : tg[pos];
    acc += trans[et * Tsz + st];
  }
  for (int l = j; l < len; l += 64)
    acc += fb[(size_t)l * Tsz + tg[l]];
  float gold = rl(wave_sum(acc), 0);

  if (j == 0) diff_out[b] = fwd_score - gold;
}

// loss = mean(diff)
__global__ __launch_bounds__(Bsz) void crf_final_kernel(
    const float* __restrict__ diff, float* __restrict__ out)
{
  int tid = threadIdx.x;
  float v = diff[tid];
  __shared__ float wred[8];
  float s = wave_sum(v);
  int wave = tid >> 6, lane = tid & 63;
  if (lane == 0) wred[wave] = s;
  __syncthreads();
  if (tid == 0) {
    float t = 0.f;
    #pragma unroll
    for (int i = 0; i < 8; ++i) t += wred[i];
    out[0] = t * (1.0f / Bsz);
  }
}

extern "C" void kernel_launch(void* const* d_in, const int* in_sizes, int n_in,
                              void* d_out, int out_size, void* d_ws, size_t ws_size,
                              hipStream_t stream) {
  const float* feats = (const float*)d_in[0];
  const float* trans = (const float*)d_in[1];
  const int*   tags  = (const int*)d_in[2];
  const int*   lens  = (const int*)d_in[3];
  float* out  = (float*)d_out;
  float* diff = (float*)d_ws;

  crf_fwd_kernel<<<Bsz, 64, 0, stream>>>(feats, trans, tags, lens, diff);
  crf_final_kernel<<<1, Bsz, 0, stream>>>(diff, out);
}

// Round 5
// 449.351 us; speedup vs baseline: 2.1268x; 2.1268x over previous
//
#include <hip/hip_runtime.h>

#define Bsz 512
#define Lsz 512
#define Tsz 128
#define TAG_START 126
#define TAG_STOP 127
#define SPB 16            // sequences per block
#define UPITCH 136        // u_lds row pitch in bf16 elems (128 + 8 pad: kills bank conflicts)

typedef __attribute__((ext_vector_type(8))) short short8;   // 8 bf16 = one MFMA A/B frag
typedef __attribute__((ext_vector_type(4))) float f32x4;    // MFMA C/D frag

// Barrier draining ONLY LDS (lgkmcnt) - global prefetch loads stay in flight.
__device__ __forceinline__ void lds_barrier() {
  asm volatile("s_waitcnt lgkmcnt(0)\n\ts_barrier" ::: "memory");
}
// f32 -> bf16 (round-half-up), packed pair
__device__ __forceinline__ unsigned pack_bf16(float lo, float hi) {
  unsigned a = (__float_as_uint(lo) + 0x8000u) >> 16;
  unsigned b = (__float_as_uint(hi) + 0x8000u) & 0xFFFF0000u;
  return b | a;
}
__device__ __forceinline__ float bf16lo(unsigned d) { return __uint_as_float(d << 16); }
__device__ __forceinline__ float bf16hi(unsigned d) { return __uint_as_float(d & 0xFFFF0000u); }

// One block = 16 sequences, 256 threads = 4 waves.
// Per step: P(128x16) = expT(128x128) . U(128x16) via 8 mfma_f32_16x16x32_bf16
// per wave (2 M-tiles x 4 K-chunks). U kept in LDS as bf16 in B-frag order.
// Carry: u_{t+1} = P_t * rcp(eta_t) * exp(emit_t), m += log(eta_t),
//        eta_t = u_t[0]+u_t[1] (any positive per-seq eta is exact algebra);
//        fv_{len-1} = log(u_len) + m_len, captured by cndmask at t==len-1.
__global__ __launch_bounds__(256) void crf_fwd_kernel(
    const float* __restrict__ feats, const float* __restrict__ trans,
    const int* __restrict__ tags, const int* __restrict__ lens,
    float* __restrict__ diff_out)
{
  __shared__ __align__(16) unsigned short u_lds[2][SPB][UPITCH];
  __shared__ float red[4][SPB];
  __shared__ float gold_sh[SPB];
  __shared__ int msh;

  const int g    = blockIdx.x;
  const int tid  = threadIdx.x;
  const int w    = tid >> 6;      // wave: owns M-tiles 2w, 2w+1
  const int lane = tid & 63;
  const int q    = lane >> 4;     // quad
  const int s    = lane & 15;     // column role: seq-in-block / MFMA n / A-row m
  const int seq  = g * SPB + s;
  const int lenc = lens[seq];

  if (tid == 0) msh = 1;
  __syncthreads();
  if (tid < SPB) atomicMax(&msh, lens[g * SPB + tid]);
  for (int i = tid; i < 2 * SPB * UPITCH; i += 256)
    ((unsigned short*)u_lds)[i] = 0;
  __syncthreads();
  const int maxlen = msh;
  if (tid < SPB) u_lds[0][tid][TAG_START] = 0x3F80;   // bf16 1.0: u0 = e_START
  __syncthreads();

  // A-fragments: af[i][c] = exp(trans[row][k]) bf16, row = (2w+i)*16 + s,
  // k = 32c + 8q + j  (A layout: m = lane&15, k = quad*8 + j)
  short8 af[2][4];
  #pragma unroll
  for (int i = 0; i < 2; ++i) {
    const float* tr = trans + (size_t)((2 * w + i) * 16 + s) * Tsz + q * 8;
    #pragma unroll
    for (int c = 0; c < 4; ++c) {
      float4 x = *(const float4*)(tr + c * 32);
      float4 y = *(const float4*)(tr + c * 32 + 4);
      union { unsigned u[4]; short8 v; } cv;
      cv.u[0] = pack_bf16(__expf(x.x), __expf(x.y));
      cv.u[1] = pack_bf16(__expf(x.z), __expf(x.w));
      cv.u[2] = pack_bf16(__expf(y.x), __expf(y.y));
      cv.u[3] = pack_bf16(__expf(y.z), __expf(y.w));
      af[i][c] = cv.v;
    }
  }

  // Emit gather offsets: this lane's 8 C-entries are (row = (2w+i)*16+4q+r, col = s)
  unsigned off0[8];
  #pragma unroll
  for (int i = 0; i < 2; ++i)
    #pragma unroll
    for (int r = 0; r < 4; ++r)
      off0[i * 4 + r] = (unsigned)seq * (Lsz * Tsz) + (2 * w + i) * 16 + 4 * q + r;

  float pfa[8], pfb[8];
  { int t1 = (1 < maxlen) ? 1 : 0;
    #pragma unroll
    for (int i = 0; i < 8; ++i) pfa[i] = feats[off0[i]];
    #pragma unroll
    for (int i = 0; i < 8; ++i) pfb[i] = feats[off0[i] + (unsigned)t1 * Tsz]; }

  float m_run = 0.0f, mcap = 0.0f;
  float ucap[8];
  #pragma unroll
  for (int i = 0; i < 8; ++i) ucap[i] = 1.0f;

#define STEP(T, PF, BR, BW)                                                    \
  { const int t_ = (T);                                                        \
    short8 bq0 = *(const short8*)&u_lds[BR][s][0 * 32 + q * 8];                \
    short8 bq1 = *(const short8*)&u_lds[BR][s][1 * 32 + q * 8];                \
    short8 bq2 = *(const short8*)&u_lds[BR][s][2 * 32 + q * 8];                \
    short8 bq3 = *(const short8*)&u_lds[BR][s][3 * 32 + q * 8];                \
    unsigned ud = *(const unsigned*)&u_lds[BR][s][0];                          \
    float eta = bf16lo(ud) + bf16hi(ud);                                       \
    if (t_ == 0) eta = 1.0f;                                                   \
    float ee[8];                                                               \
    _Pragma("unroll") for (int i = 0; i < 8; ++i) ee[i] = __expf(PF[i]);       \
    f32x4 acc0 = {0.f, 0.f, 0.f, 0.f}, acc1 = {0.f, 0.f, 0.f, 0.f};            \
    acc0 = __builtin_amdgcn_mfma_f32_16x16x32_bf16(af[0][0], bq0, acc0, 0,0,0);\
    acc1 = __builtin_amdgcn_mfma_f32_16x16x32_bf16(af[1][0], bq0, acc1, 0,0,0);\
    acc0 = __builtin_amdgcn_mfma_f32_16x16x32_bf16(af[0][1], bq1, acc0, 0,0,0);\
    acc1 = __builtin_amdgcn_mfma_f32_16x16x32_bf16(af[1][1], bq1, acc1, 0,0,0);\
    acc0 = __builtin_amdgcn_mfma_f32_16x16x32_bf16(af[0][2], bq2, acc0, 0,0,0);\
    acc1 = __builtin_amdgcn_mfma_f32_16x16x32_bf16(af[1][2], bq2, acc1, 0,0,0);\
    acc0 = __builtin_amdgcn_mfma_f32_16x16x32_bf16(af[0][3], bq3, acc0, 0,0,0);\
    acc1 = __builtin_amdgcn_mfma_f32_16x16x32_bf16(af[1][3], bq3, acc1, 0,0,0);\
    int tp = t_ + 2; if (tp >= maxlen) tp = maxlen - 1;                        \
    unsigned toff = (unsigned)tp * Tsz;                                        \
    _Pragma("unroll") for (int i = 0; i < 8; ++i) PF[i] = feats[off0[i] + toff];\
    float rce = __builtin_amdgcn_rcpf(eta);                                    \
    bool capt = (t_ == lenc - 1);                                              \
    float uv[8];                                                               \
    _Pragma("unroll") for (int i = 0; i < 4; ++i) {                            \
      uv[i]     = acc0[i] * rce * ee[i];                                       \
      uv[4 + i] = acc1[i] * rce * ee[4 + i];                                   \
    }                                                                          \
    _Pragma("unroll") for (int i = 0; i < 8; ++i)                              \
      ucap[i] = capt ? uv[i] : ucap[i];                                        \
    m_run += __logf(eta);                                                      \
    mcap = capt ? m_run : mcap;                                                \
    unsigned short* dst = &u_lds[BW][s][0];                                    \
    *(unsigned*)&dst[(2 * w + 0) * 16 + 4 * q]     = pack_bf16(uv[0], uv[1]);  \
    *(unsigned*)&dst[(2 * w + 0) * 16 + 4 * q + 2] = pack_bf16(uv[2], uv[3]);  \
    *(unsigned*)&dst[(2 * w + 1) * 16 + 4 * q]     = pack_bf16(uv[4], uv[5]);  \
    *(unsigned*)&dst[(2 * w + 1) * 16 + 4 * q + 2] = pack_bf16(uv[6], uv[7]);  \
    lds_barrier();                                                             \
  }

  for (int t = 0; t < maxlen; t += 2) {
    STEP(t, pfa, 0, 1)
    if (t + 1 < maxlen) STEP(t + 1, pfb, 1, 0)   // maxlen uniform -> no divergence
  }
#undef STEP

  __syncthreads();

  // fv for this lane's 8 (row, col=s) entries; terminal adds trans[START,row]
  float fvv[8];
  #pragma unroll
  for (int i = 0; i < 2; ++i)
    #pragma unroll
    for (int r = 0; r < 4; ++r) {
      int row = (2 * w + i) * 16 + 4 * q + r;
      fvv[i * 4 + r] = __logf(ucap[i * 4 + r]) + mcap + trans[TAG_START * Tsz + row];
    }
  float mx = fvv[0];
  #pragma unroll
  for (int i = 1; i < 8; ++i) mx = fmaxf(mx, fvv[i]);
  mx = fmaxf(mx, __shfl_xor(mx, 16, 64));
  mx = fmaxf(mx, __shfl_xor(mx, 32, 64));
  if (q == 0) red[w][s] = mx;
  __syncthreads();
  float gmx = fmaxf(fmaxf(red[0][s], red[1][s]), fmaxf(red[2][s], red[3][s]));
  __syncthreads();
  float se = 0.f;
  #pragma unroll
  for (int i = 0; i < 8; ++i) se += __expf(fvv[i] - gmx);
  se += __shfl_xor(se, 16, 64);
  se += __shfl_xor(se, 32, 64);
  if (q == 0) red[w][s] = se;
  __syncthreads();
  float fwd_score = gmx + __logf((red[0][s] + red[1][s]) + (red[2][s] + red[3][s]));

  // ---- gold score: wave w handles seqs 4w+q; 16 lanes per seq ----
  {
    int jj = 4 * w + q;
    int gs2 = g * SPB + jj;
    int lenj = lens[gs2];
    const int* tg = tags + (size_t)gs2 * Lsz;
    const float* fbj = feats + (size_t)gs2 * (Lsz * Tsz);
    float acc = 0.f;
    for (int pos = s; pos <= lenj; pos += 16) {
      int st = (pos == 0)    ? TAG_START : tg[pos - 1];
      int et = (pos == lenj) ? TAG_STOP  : tg[pos];
      acc += trans[et * Tsz + st];
    }
    for (int l = s; l < lenj; l += 16)
      acc += fbj[(size_t)l * Tsz + tg[l]];
    #pragma unroll
    for (int off = 1; off < 16; off <<= 1) acc += __shfl_xor(acc, off, 64);
    if (s == 0) gold_sh[jj] = acc;
  }
  __syncthreads();
  if (w == 0 && q == 0)
    diff_out[g * SPB + s] = fwd_score - gold_sh[s];
}

// loss = mean(diff)
__global__ __launch_bounds__(Bsz) void crf_final_kernel(
    const float* __restrict__ diff, float* __restrict__ out)
{
  int tid = threadIdx.x;
  float v = diff[tid];
  __shared__ float wred[8];
  float sum = v;
  #pragma unroll
  for (int off = 32; off > 0; off >>= 1) sum += __shfl_down(sum, off, 64);
  int wave = tid >> 6, lane = tid & 63;
  if (lane == 0) wred[wave] = sum;
  __syncthreads();
  if (tid == 0) {
    float t = 0.f;
    #pragma unroll
    for (int i = 0; i < 8; ++i) t += wred[i];
    out[0] = t * (1.0f / Bsz);
  }
}

extern "C" void kernel_launch(void* const* d_in, const int* in_sizes, int n_in,
                              void* d_out, int out_size, void* d_ws, size_t ws_size,
                              hipStream_t stream) {
  const float* feats = (const float*)d_in[0];
  const float* trans = (const float*)d_in[1];
  const int*   tags  = (const int*)d_in[2];
  const int*   lens  = (const int*)d_in[3];
  float* out  = (float*)d_out;
  float* diff = (float*)d_ws;

  crf_fwd_kernel<<<Bsz / SPB, 256, 0, stream>>>(feats, trans, tags, lens, diff);
  crf_final_kernel<<<1, Bsz, 0, stream>>>(diff, out);
}

// Round 6
// 407.186 us; speedup vs baseline: 2.3471x; 1.1036x over previous
//
#include <hip/hip_runtime.h>

#define Bsz 512
#define Lsz 512
#define Tsz 128
#define TAG_START 126
#define TAG_STOP 127
#define SPB 16            // sequences per block
#define UPITCH 136        // u_lds row pitch in bf16 elems (128 + 8 pad)

typedef __attribute__((ext_vector_type(8))) short short8;   // 8 bf16 = MFMA A/B frag
typedef __attribute__((ext_vector_type(4))) float f32x4;    // MFMA C/D frag

// Barrier draining ONLY LDS (lgkmcnt) - global prefetch loads stay in flight.
__device__ __forceinline__ void lds_barrier() {
  asm volatile("s_waitcnt lgkmcnt(0)\n\ts_barrier" ::: "memory");
}
__device__ __forceinline__ unsigned pack_bf16(float lo, float hi) {
  unsigned a = (__float_as_uint(lo) + 0x8000u) >> 16;
  unsigned b = (__float_as_uint(hi) + 0x8000u) & 0xFFFF0000u;
  return b | a;
}
__device__ __forceinline__ float bf16lo(unsigned d) { return __uint_as_float(d << 16); }
__device__ __forceinline__ float bf16hi(unsigned d) { return __uint_as_float(d & 0xFFFF0000u); }

// One block = 16 sequences, 256 threads = 4 waves.
// Per step: P(128x16) = expT(128x128) . U(128x16), 8 mfma_f32_16x16x32_bf16
// per wave. U in LDS (bf16, B-frag order). Carry (validated absmax=0):
//   u_{t+1} = P_t * rcp(eta_t) * exp(emit_t),  m += log(eta_t),
//   eta_t = u_t[0]+u_t[1] (per column),  fv captured at t == len-1.
// Emits: 2x global_load_dwordx4 per lane per step, 4-deep static ring,
// exp() precomputed one step ahead (nothing vmcnt-bound on the chain top).
__global__ __launch_bounds__(256) void crf_fwd_kernel(
    const float* __restrict__ feats, const float* __restrict__ trans,
    const int* __restrict__ tags, const int* __restrict__ lens,
    float* __restrict__ diff_out)
{
  __shared__ __align__(16) unsigned short u_lds[2][SPB][UPITCH];
  __shared__ float red[4][SPB];
  __shared__ float gold_sh[SPB];
  __shared__ int msh;

  const int g    = blockIdx.x;
  const int tid  = threadIdx.x;
  const int w    = tid >> 6;      // wave: owns M-tiles 2w, 2w+1
  const int lane = tid & 63;
  const int q    = lane >> 4;     // quad
  const int s    = lane & 15;     // column: seq-in-block / MFMA n / A-row m
  const int seq  = g * SPB + s;
  const int lenc = lens[seq];
  const int lim  = lenc - 1;

  if (tid == 0) msh = 1;
  __syncthreads();
  if (tid < SPB) atomicMax(&msh, lens[g * SPB + tid]);
  for (int i = tid; i < 2 * SPB * UPITCH; i += 256)
    ((unsigned short*)u_lds)[i] = 0;
  __syncthreads();
  const int maxlen = msh;
  if (tid < SPB) u_lds[0][tid][TAG_START] = 0x3F80;   // bf16 1.0
  __syncthreads();

  // A-frags: af[i][c] = exp(trans[(2w+i)*16+s][32c+8q+j]) bf16
  short8 af[2][4];
  #pragma unroll
  for (int i = 0; i < 2; ++i) {
    const float* tr = trans + (size_t)((2 * w + i) * 16 + s) * Tsz + q * 8;
    #pragma unroll
    for (int c = 0; c < 4; ++c) {
      float4 x = *(const float4*)(tr + c * 32);
      float4 y = *(const float4*)(tr + c * 32 + 4);
      union { unsigned u[4]; short8 v; } cv;
      cv.u[0] = pack_bf16(__expf(x.x), __expf(x.y));
      cv.u[1] = pack_bf16(__expf(x.z), __expf(x.w));
      cv.u[2] = pack_bf16(__expf(y.x), __expf(y.y));
      cv.u[3] = pack_bf16(__expf(y.z), __expf(y.w));
      af[i][c] = cv.v;
    }
  }

  // Emit pointers: lane's 8 C-entries = rows (2w+i)*16+4q+[0..4), col s.
  const float* fp0 = feats + (size_t)seq * (Lsz * Tsz) + (2 * w + 0) * 16 + 4 * q;
  const float* fp1 = feats + (size_t)seq * (Lsz * Tsz) + (2 * w + 1) * 16 + 4 * q;

  // 4-deep static ring: slot k holds emit row (t with t%4==k), clamped to lim
  float4 pa0, pb0, pa1, pb1, pa2, pb2, pa3, pb3;
  { int r1 = (1 < lim) ? 1 : lim, r2 = (2 < lim) ? 2 : lim, r3 = (3 < lim) ? 3 : lim;
    if (lim < 1) r1 = r2 = r3 = lim;
    pa0 = *(const float4*)(fp0);                       pb0 = *(const float4*)(fp1);
    pa1 = *(const float4*)(fp0 + ((size_t)r1 << 7));   pb1 = *(const float4*)(fp1 + ((size_t)r1 << 7));
    pa2 = *(const float4*)(fp0 + ((size_t)r2 << 7));   pb2 = *(const float4*)(fp1 + ((size_t)r2 << 7));
    pa3 = *(const float4*)(fp0 + ((size_t)r3 << 7));   pb3 = *(const float4*)(fp1 + ((size_t)r3 << 7)); }

  float ee[8] = {__expf(pa0.x), __expf(pa0.y), __expf(pa0.z), __expf(pa0.w),
                 __expf(pb0.x), __expf(pb0.y), __expf(pb0.z), __expf(pb0.w)};

  float m_run = 0.0f, mcap = 0.0f;
  float ucap[8];
  #pragma unroll
  for (int i = 0; i < 8; ++i) ucap[i] = 1.0f;

  // STEP: PA/PB = this step's ring slot (reloaded for t+4);
  //        NA/NB = next step's slot (already resident) -> ee for t+1.
#define STEP(T, PA, PB, NA, NB, BR, BW)                                        \
  { const int t_ = (T);                                                        \
    short8 bq0 = *(const short8*)&u_lds[BR][s][0 * 32 + q * 8];                \
    short8 bq1 = *(const short8*)&u_lds[BR][s][1 * 32 + q * 8];                \
    short8 bq2 = *(const short8*)&u_lds[BR][s][2 * 32 + q * 8];                \
    short8 bq3 = *(const short8*)&u_lds[BR][s][3 * 32 + q * 8];                \
    unsigned ud = *(const unsigned*)&u_lds[BR][s][0];                          \
    int tp = t_ + 4; tp = (tp < lim) ? tp : lim;                               \
    PA = *(const float4*)(fp0 + ((size_t)tp << 7));                            \
    PB = *(const float4*)(fp1 + ((size_t)tp << 7));                            \
    f32x4 acc0 = {0.f, 0.f, 0.f, 0.f}, acc1 = {0.f, 0.f, 0.f, 0.f};            \
    acc0 = __builtin_amdgcn_mfma_f32_16x16x32_bf16(af[0][0], bq0, acc0, 0,0,0);\
    acc1 = __builtin_amdgcn_mfma_f32_16x16x32_bf16(af[1][0], bq0, acc1, 0,0,0);\
    acc0 = __builtin_amdgcn_mfma_f32_16x16x32_bf16(af[0][1], bq1, acc0, 0,0,0);\
    acc1 = __builtin_amdgcn_mfma_f32_16x16x32_bf16(af[1][1], bq1, acc1, 0,0,0);\
    acc0 = __builtin_amdgcn_mfma_f32_16x16x32_bf16(af[0][2], bq2, acc0, 0,0,0);\
    acc1 = __builtin_amdgcn_mfma_f32_16x16x32_bf16(af[1][2], bq2, acc1, 0,0,0);\
    acc0 = __builtin_amdgcn_mfma_f32_16x16x32_bf16(af[0][3], bq3, acc0, 0,0,0);\
    acc1 = __builtin_amdgcn_mfma_f32_16x16x32_bf16(af[1][3], bq3, acc1, 0,0,0);\
    float eta = bf16lo(ud) + bf16hi(ud);                                       \
    if (t_ == 0) eta = 1.0f;                                                   \
    float rce = __builtin_amdgcn_rcpf(eta);                                    \
    bool capt = (t_ == lim);                                                   \
    float uv[8];                                                               \
    _Pragma("unroll") for (int i = 0; i < 4; ++i) {                            \
      uv[i]     = acc0[i] * rce * ee[i];                                       \
      uv[4 + i] = acc1[i] * rce * ee[4 + i];                                   \
    }                                                                          \
    _Pragma("unroll") for (int i = 0; i < 8; ++i)                              \
      ucap[i] = capt ? uv[i] : ucap[i];                                        \
    m_run += __logf(eta);                                                      \
    mcap = capt ? m_run : mcap;                                                \
    unsigned short* dst = &u_lds[BW][s][0];                                    \
    *(unsigned*)&dst[(2 * w + 0) * 16 + 4 * q]     = pack_bf16(uv[0], uv[1]);  \
    *(unsigned*)&dst[(2 * w + 0) * 16 + 4 * q + 2] = pack_bf16(uv[2], uv[3]);  \
    *(unsigned*)&dst[(2 * w + 1) * 16 + 4 * q]     = pack_bf16(uv[4], uv[5]);  \
    *(unsigned*)&dst[(2 * w + 1) * 16 + 4 * q + 2] = pack_bf16(uv[6], uv[7]);  \
    ee[0] = __expf(NA.x); ee[1] = __expf(NA.y);                                \
    ee[2] = __expf(NA.z); ee[3] = __expf(NA.w);                                \
    ee[4] = __expf(NB.x); ee[5] = __expf(NB.y);                                \
    ee[6] = __expf(NB.z); ee[7] = __expf(NB.w);                                \
    lds_barrier();                                                             \
  }

  for (int t = 0; t < maxlen; t += 4) {
    STEP(t + 0, pa0, pb0, pa1, pb1, 0, 1)
    STEP(t + 1, pa1, pb1, pa2, pb2, 1, 0)
    STEP(t + 2, pa2, pb2, pa3, pb3, 0, 1)
    STEP(t + 3, pa3, pb3, pa0, pb0, 1, 0)
  }
#undef STEP

  __syncthreads();

  // fv + terminal logsumexp over 128 tags (col = s)
  float fvv[8];
  #pragma unroll
  for (int i = 0; i < 2; ++i)
    #pragma unroll
    for (int r = 0; r < 4; ++r) {
      int row = (2 * w + i) * 16 + 4 * q + r;
      fvv[i * 4 + r] = __logf(ucap[i * 4 + r]) + mcap + trans[TAG_START * Tsz + row];
    }
  float mx = fvv[0];
  #pragma unroll
  for (int i = 1; i < 8; ++i) mx = fmaxf(mx, fvv[i]);
  mx = fmaxf(mx, __shfl_xor(mx, 16, 64));
  mx = fmaxf(mx, __shfl_xor(mx, 32, 64));
  if (q == 0) red[w][s] = mx;
  __syncthreads();
  float gmx = fmaxf(fmaxf(red[0][s], red[1][s]), fmaxf(red[2][s], red[3][s]));
  __syncthreads();
  float se = 0.f;
  #pragma unroll
  for (int i = 0; i < 8; ++i) se += __expf(fvv[i] - gmx);
  se += __shfl_xor(se, 16, 64);
  se += __shfl_xor(se, 32, 64);
  if (q == 0) red[w][s] = se;
  __syncthreads();
  float fwd_score = gmx + __logf((red[0][s] + red[1][s]) + (red[2][s] + red[3][s]));

  // ---- gold score: wave w handles seqs 4w+q; 16 lanes per seq ----
  {
    int jj = 4 * w + q;
    int gs2 = g * SPB + jj;
    int lenj = lens[gs2];
    const int* tg = tags + (size_t)gs2 * Lsz;
    const float* fbj = feats + (size_t)gs2 * (Lsz * Tsz);
    float acc = 0.f;
    for (int pos = s; pos <= lenj; pos += 16) {
      int st = (pos == 0)    ? TAG_START : tg[pos - 1];
      int et = (pos == lenj) ? TAG_STOP  : tg[pos];
      acc += trans[et * Tsz + st];
    }
    for (int l = s; l < lenj; l += 16)
      acc += fbj[(size_t)l * Tsz + tg[l]];
    #pragma unroll
    for (int off = 1; off < 16; off <<= 1) acc += __shfl_xor(acc, off, 64);
    if (s == 0) gold_sh[jj] = acc;
  }
  __syncthreads();
  if (w == 0 && q == 0)
    diff_out[g * SPB + s] = fwd_score - gold_sh[s];
}

// loss = mean(diff)
__global__ __launch_bounds__(Bsz) void crf_final_kernel(
    const float* __restrict__ diff, float* __restrict__ out)
{
  int tid = threadIdx.x;
  float v = diff[tid];
  __shared__ float wred[8];
  float sum = v;
  #pragma unroll
  for (int off = 32; off > 0; off >>= 1) sum += __shfl_down(sum, off, 64);
  int wave = tid >> 6, lane = tid & 63;
  if (lane == 0) wred[wave] = sum;
  __syncthreads();
  if (tid == 0) {
    float t = 0.f;
    #pragma unroll
    for (int i = 0; i < 8; ++i) t += wred[i];
    out[0] = t * (1.0f / Bsz);
  }
}

extern "C" void kernel_launch(void* const* d_in, const int* in_sizes, int n_in,
                              void* d_out, int out_size, void* d_ws, size_t ws_size,
                              hipStream_t stream) {
  const float* feats = (const float*)d_in[0];
  const float* trans = (const float*)d_in[1];
  const int*   tags  = (const int*)d_in[2];
  const int*   lens  = (const int*)d_in[3];
  float* out  = (float*)d_out;
  float* diff = (float*)d_ws;

  crf_fwd_kernel<<<Bsz / SPB, 256, 0, stream>>>(feats, trans, tags, lens, diff);
  crf_final_kernel<<<1, Bsz, 0, stream>>>(diff, out);
}